// Round 1
// baseline (604.473 us; speedup 1.0000x reference)
//
#include <hip/hip_runtime.h>
#include <hip/hip_bf16.h>
#include <math.h>

#define HW 3136            // 56*56
#define HW4 784            // float4s per plane
#define CCH 256
#define RCH 16
#define NTF 64             // n_batch * T
#define EPS 1e-5f

// ---------------------------------------------------------------- K1: spatial mean
__global__ __launch_bounds__(256) void k_mean(const float* __restrict__ x,
                                              float* __restrict__ xmean) {
    const int row = blockIdx.x;                        // nt*256 + c
    const float4* p4 = (const float4*)(x + (size_t)row * HW);
    float s = 0.f;
    for (int i = threadIdx.x; i < HW4; i += 256) {
        float4 v = p4[i];
        s += (v.x + v.y) + (v.z + v.w);
    }
    for (int off = 32; off > 0; off >>= 1) s += __shfl_down(s, off);
    __shared__ float red[4];
    const int wid = threadIdx.x >> 6;
    if ((threadIdx.x & 63) == 0) red[wid] = s;
    __syncthreads();
    if (threadIdx.x == 0)
        xmean[row] = (red[0] + red[1] + red[2] + red[3]) * (1.f / 3136.f);
}

// ---------------------------------------------------------------- K2: excitation chain
__global__ __launch_bounds__(256) void k_excite(
    const float* __restrict__ xmean, const float* __restrict__ w_sq,
    const float* __restrict__ w_ac1, const float* __restrict__ w_ex,
    const float* __restrict__ abn_g, const float* __restrict__ abn_b,
    const float* __restrict__ abn_m, const float* __restrict__ abn_v,
    float* __restrict__ geff) {
    __shared__ float g1[64][16];
    __shared__ float g2[64][16];
    const int tid = threadIdx.x;
    // squeeze: [64,256] @ w_sq^T -> [64,16]
    for (int idx = tid; idx < 64 * 16; idx += 256) {
        const int nt = idx >> 4, j = idx & 15;
        float s = 0.f;
        for (int c = 0; c < 256; ++c) s = fmaf(xmean[nt * 256 + c], w_sq[j * 256 + c], s);
        g1[nt][j] = s;
    }
    __syncthreads();
    // temporal conv over T (pad=1), per batch nn
    for (int idx = tid; idx < 64 * 16; idx += 256) {
        const int nt = idx >> 4, o = idx & 15;
        const int nn = nt >> 3, t = nt & 7;
        float s = 0.f;
        #pragma unroll
        for (int k = 0; k < 3; ++k) {
            const int ts = t + k - 1;
            if (ts < 0 || ts >= 8) continue;
            for (int i = 0; i < 16; ++i)
                s = fmaf(w_ac1[(o * 16 + i) * 3 + k], g1[nn * 8 + ts][i], s);
        }
        g2[nt][o] = s;
    }
    __syncthreads();
    // expand + BN + sigmoid - 0.5 ; store geff = 1 + g
    for (int idx = tid; idx < 64 * 256; idx += 256) {
        const int nt = idx >> 8, c = idx & 255;
        float s = 0.f;
        #pragma unroll
        for (int j = 0; j < 16; ++j) s = fmaf(g2[nt][j], w_ex[c * 16 + j], s);
        const float sc = abn_g[c] * rsqrtf(abn_v[c] + EPS);
        const float z = (s - abn_m[c]) * sc + abn_b[c];
        const float sig = 1.f / (1.f + expf(-z));
        geff[idx] = 0.5f + sig;      // 1 + (sigmoid - 0.5)
    }
}

// ---------------------------------------------------------------- K3: x_p2 -> 1x1 conv -> BN1
__global__ __launch_bounds__(256) void k_bottleneck(
    const float* __restrict__ x, const float* __restrict__ geff,
    const float* __restrict__ w_c1, const float* __restrict__ bn1_g,
    const float* __restrict__ bn1_b, const float* __restrict__ bn1_m,
    const float* __restrict__ bn1_v, float* __restrict__ bot) {
    __shared__ float wl[256][16];        // [c][o] effective weights (geff folded)
    __shared__ float s1s[16], b1s[16];
    const int nt = blockIdx.y;
    const int chunk = blockIdx.x;        // 7 chunks of 512 pixels
    const int tid = threadIdx.x;
    for (int idx = tid; idx < 4096; idx += 256) {
        const int c = idx >> 4, o = idx & 15;
        wl[c][o] = w_c1[o * 256 + c] * geff[nt * 256 + c];
    }
    if (tid < 16) {
        const float s = bn1_g[tid] * rsqrtf(bn1_v[tid] + EPS);
        s1s[tid] = s;
        b1s[tid] = bn1_b[tid] - bn1_m[tid] * s;
    }
    __syncthreads();
    const int p0 = chunk * 512 + tid;
    const int p1 = p0 + 256;
    const bool v0 = p0 < HW, v1 = p1 < HW;
    const float* xb = x + (size_t)nt * (256 * HW);
    float acc0[16], acc1[16];
    #pragma unroll
    for (int o = 0; o < 16; ++o) { acc0[o] = 0.f; acc1[o] = 0.f; }
    for (int c = 0; c < 256; ++c) {
        const float x0 = v0 ? xb[c * HW + p0] : 0.f;
        const float x1 = v1 ? xb[c * HW + p1] : 0.f;
        #pragma unroll
        for (int o = 0; o < 16; ++o) {
            const float w = wl[c][o];
            acc0[o] = fmaf(x0, w, acc0[o]);
            acc1[o] = fmaf(x1, w, acc1[o]);
        }
    }
    float* bb = bot + (size_t)nt * (16 * HW);
    #pragma unroll
    for (int o = 0; o < 16; ++o) {
        if (v0) bb[o * HW + p0] = acc0[o] * s1s[o] + b1s[o];
        if (v1) bb[o * HW + p1] = acc1[o] * s1s[o] + b1s[o];
    }
}

// ---------------------------------------------------------------- K4: depthwise 3x3 + 9-stats
// stats layout per plane: 0 total, 1 row0, 2 row55, 3 col0, 4 col55,
//                         5 v[0][0], 6 v[0][55], 7 v[55][0], 8 v[55][55]
__global__ __launch_bounds__(256) void k_dwstats(
    const float* __restrict__ bot, const float* __restrict__ w_c2,
    float* __restrict__ statsB, float* __restrict__ statsCB) {
    const int plane = blockIdx.x;         // nt*16 + ch
    const int ch = plane & 15;
    __shared__ float tile[58][58];
    const int tid = threadIdx.x;
    for (int idx = tid; idx < 58 * 58; idx += 256) {
        const int yy = idx / 58, xx = idx % 58;
        float v = 0.f;
        if (yy >= 1 && yy <= 56 && xx >= 1 && xx <= 56)
            v = bot[(size_t)plane * HW + (yy - 1) * 56 + (xx - 1)];
        tile[yy][xx] = v;
    }
    __syncthreads();
    float w2[9];
    #pragma unroll
    for (int k = 0; k < 9; ++k) w2[k] = w_c2[ch * 9 + k];
    float a[10];
    #pragma unroll
    for (int k = 0; k < 10; ++k) a[k] = 0.f;
    for (int p = tid; p < HW; p += 256) {
        const int y = p / 56, xc = p % 56;
        const float v = tile[y + 1][xc + 1];
        float cv = 0.f;
        #pragma unroll
        for (int ky = 0; ky < 3; ++ky)
            #pragma unroll
            for (int kx = 0; kx < 3; ++kx)
                cv = fmaf(w2[ky * 3 + kx], tile[y + ky][xc + kx], cv);
        a[0] += v; a[1] += cv;
        if (y == 0)   { a[2] += v; a[3] += cv; }
        if (y == 55)  { a[4] += v; a[5] += cv; }
        if (xc == 0)  { a[6] += v; a[7] += cv; }
        if (xc == 55) { a[8] += v; a[9] += cv; }
        if (y == 0  && xc == 0)  { statsB[plane * 9 + 5] = v; statsCB[plane * 9 + 5] = cv; }
        if (y == 0  && xc == 55) { statsB[plane * 9 + 6] = v; statsCB[plane * 9 + 6] = cv; }
        if (y == 55 && xc == 0)  { statsB[plane * 9 + 7] = v; statsCB[plane * 9 + 7] = cv; }
        if (y == 55 && xc == 55) { statsB[plane * 9 + 8] = v; statsCB[plane * 9 + 8] = cv; }
    }
    #pragma unroll
    for (int k = 0; k < 10; ++k)
        for (int off = 32; off > 0; off >>= 1) a[k] += __shfl_down(a[k], off);
    __shared__ float red[4][10];
    const int wid = tid >> 6;
    if ((tid & 63) == 0) {
        #pragma unroll
        for (int k = 0; k < 10; ++k) red[wid][k] = a[k];
    }
    __syncthreads();
    if (tid == 0) {
        float r[10];
        #pragma unroll
        for (int k = 0; k < 10; ++k)
            r[k] = red[0][k] + red[1][k] + red[2][k] + red[3][k];
        statsB[plane * 9 + 0] = r[0]; statsCB[plane * 9 + 0] = r[1];
        statsB[plane * 9 + 1] = r[2]; statsCB[plane * 9 + 1] = r[3];
        statsB[plane * 9 + 2] = r[4]; statsCB[plane * 9 + 2] = r[5];
        statsB[plane * 9 + 3] = r[6]; statsCB[plane * 9 + 3] = r[7];
        statsB[plane * 9 + 4] = r[8]; statsCB[plane * 9 + 4] = r[9];
    }
}

// ---------------------------------------------------------------- K5: everything downstream
__global__ __launch_bounds__(256) void k_finish(
    const float* __restrict__ statsB, const float* __restrict__ statsCB,
    const float* __restrict__ w_c8s, const float* __restrict__ b_c8s,
    const float* __restrict__ w_c8t, const float* __restrict__ b_c8t,
    const float* __restrict__ w_cs, const float* __restrict__ b_cs,
    const float* __restrict__ w_cst, const float* __restrict__ b_cst,
    const float* __restrict__ w_up, const float* __restrict__ b_up,
    const float* __restrict__ w_c3, const float* __restrict__ bn3_g,
    const float* __restrict__ bn3_b, const float* __restrict__ bn3_m,
    const float* __restrict__ bn3_v, const float* __restrict__ geff,
    float* __restrict__ st) {
    __shared__ float T[64][16][9];       // window sums of dfp per (frame, ch)
    __shared__ float d8pre[64][16];
    __shared__ float dspre[8][6][16];
    __shared__ float d4[8][16][4];
    __shared__ float d8[8][16][4];
    __shared__ float ds[8][16][4];
    __shared__ float dcomb[8][16][4];
    __shared__ float ufl[8][192];
    __shared__ float sel[8][16][8];
    const int tid = threadIdx.x;
    const float inv = 1.f / 3136.f;

    // phase 1: dfp stats -> 9 shifted-window totals T[ky*3+kx]
    for (int idx = tid; idx < 64 * 16; idx += 256) {
        const int f = idx >> 4, i = idx & 15;
        const int t = f & 7;
        if (t == 7) {
            #pragma unroll
            for (int k = 0; k < 9; ++k) T[f][i][k] = 0.f;
        } else {
            const float* pB = statsB + (size_t)(f * 16 + i) * 9;
            const float* pC = statsCB + (size_t)((f + 1) * 16 + i) * 9;
            float d[9];
            #pragma unroll
            for (int k = 0; k < 9; ++k) d[k] = pC[k] - pB[k];
            // (dy,dx): dy=-1 excl row55(d2), dy=+1 excl row0(d1);
            //          dx=-1 excl col55(d4), dx=+1 excl col0(d3)
            T[f][i][0] = d[0] - d[2] - d[4] + d[8];  // ky=0,kx=0
            T[f][i][1] = d[0] - d[2];                // ky=0,kx=1
            T[f][i][2] = d[0] - d[2] - d[3] + d[7];  // ky=0,kx=2
            T[f][i][3] = d[0] - d[4];                // ky=1,kx=0
            T[f][i][4] = d[0];                       // ky=1,kx=1
            T[f][i][5] = d[0] - d[3];                // ky=1,kx=2
            T[f][i][6] = d[0] - d[1] - d[4] + d[6];  // ky=2,kx=0
            T[f][i][7] = d[0] - d[1];                // ky=2,kx=1
            T[f][i][8] = d[0] - d[1] - d[3] + d[5];  // ky=2,kx=2
        }
    }
    __syncthreads();
    // phase 2a: mean of conv2d(dfp, w_c8s) + bias
    for (int idx = tid; idx < 64 * 16; idx += 256) {
        const int f = idx >> 4, o = idx & 15;
        float s = 0.f;
        for (int i = 0; i < 16; ++i)
            #pragma unroll
            for (int k = 0; k < 9; ++k)
                s = fmaf(w_c8s[(o * 16 + i) * 9 + k], T[f][i][k], s);
        d8pre[f][o] = b_c8s[o] + s * inv;
    }
    // phase 2b: mean of conv2d(dsec, w_cs) + bias
    for (int idx = tid; idx < 8 * 6 * 16; idx += 256) {
        const int nn = idx / 96;
        const int rem = idx % 96;
        const int j = rem >> 4, o = rem & 15;
        float s = 0.f;
        for (int i = 0; i < 16; ++i)
            #pragma unroll
            for (int k = 0; k < 9; ++k)
                s = fmaf(w_cs[(o * 16 + i) * 9 + k],
                         T[nn * 8 + j + 1][i][k] - T[nn * 8 + j][i][k], s);
        dspre[nn][j][o] = b_cs[o] + s * inv;
    }
    // phase 2c: d4 (torch frame-major concat scramble)
    for (int idx = tid; idx < 8 * 16 * 4; idx += 256) {
        const int a = idx >> 6, r = (idx >> 2) & 15, b = idx & 3;
        const int k = a * 4 + b;
        const int batch = k & 7, frame = 2 * (k >> 3);
        d4[a][r][b] = T[batch * 8 + frame][r][4] * inv;
    }
    __syncthreads();
    // phase 3: temporal convs
    for (int idx = tid; idx < 8 * 16 * 4; idx += 256) {
        const int nn = idx >> 6, o = (idx >> 2) & 15, tp = idx & 3;
        float s = b_c8t[o];
        #pragma unroll
        for (int k = 0; k < 3; ++k) {
            const int ti = 2 * tp + k - 1;
            if (ti < 0 || ti > 7) continue;
            for (int i = 0; i < 16; ++i)
                s = fmaf(w_c8t[(o * 16 + i) * 3 + k], d8pre[nn * 8 + ti][i], s);
        }
        d8[nn][o][tp] = s;
        float s2 = b_cst[o];
        #pragma unroll
        for (int k = 0; k < 3; ++k)
            for (int i = 0; i < 16; ++i)
                s2 = fmaf(w_cst[(o * 16 + i) * 3 + k], dspre[nn][tp + k][i], s2);
        ds[nn][o][tp] = s2;
    }
    __syncthreads();
    for (int idx = tid; idx < 8 * 16 * 4; idx += 256) {
        const int nn = idx >> 6, r = (idx >> 2) & 15, tp = idx & 3;
        dcomb[nn][r][tp] = (d4[nn][r][tp] + d8[nn][r][tp] + ds[nn][r][tp]) * (1.f / 3.f);
    }
    __syncthreads();
    // phase 4: 1x1 upsample R->3R, viewed flat [n][192]
    for (int idx = tid; idx < 8 * 48 * 4; idx += 256) {
        const int nn = idx / 192;
        const int rem = idx % 192;
        const int o = rem >> 2, t = rem & 3;
        float s = b_up[o];
        #pragma unroll
        for (int r = 0; r < 16; ++r) s = fmaf(dcomb[nn][r][t], w_up[o * 16 + r], s);
        ufl[nn][o * 4 + t] = s;
    }
    __syncthreads();
    // phase 4b: 12 -> 8 selection
    for (int idx = tid; idx < 8 * 16 * 8; idx += 256) {
        const int nn = idx >> 7, r = (idx >> 3) & 15, t = idx & 7;
        const float* u = &ufl[nn][r * 12];
        float v;
        switch (t) {
            case 0: v = u[1]; break;
            case 1: v = 0.5f * (u[2] + u[3]); break;
            case 2: v = u[4]; break;
            case 3: v = 0.5f * (u[5] + u[6]); break;
            case 4: v = u[7]; break;
            case 5: v = 0.5f * (u[8] + u[9]); break;
            case 6: v = u[10]; break;
            default: v = u[11]; break;
        }
        sel[nn][r][t] = v;
    }
    __syncthreads();
    // phase 5: expand to [64,256], BN3, sigmoid-0.5, combine with geff
    for (int idx = tid; idx < 64 * 256; idx += 256) {
        const int nt = idx >> 8, c = idx & 255;
        const int nn = nt >> 3, t = nt & 7;
        float s = 0.f;
        #pragma unroll
        for (int r = 0; r < 16; ++r) s = fmaf(sel[nn][r][t], w_c3[c * 16 + r], s);
        const float sc = bn3_g[c] * rsqrtf(bn3_v[c] + EPS);
        const float z = (s - bn3_m[c]) * sc + bn3_b[c];
        const float sig = 1.f / (1.f + expf(-z));
        st[idx] = geff[idx] * (0.5f + sig);   // (1+g)*(1+y)
    }
}

// ---------------------------------------------------------------- K6: out = x * st
__global__ __launch_bounds__(256) void k_scale_out(
    const float* __restrict__ x, const float* __restrict__ st,
    float* __restrict__ out) {
    const int total4 = NTF * CCH * HW4;   // 12,845,056
    for (int i = blockIdx.x * 256 + threadIdx.x; i < total4; i += gridDim.x * 256) {
        float4 v = ((const float4*)x)[i];
        const float sv = st[i / HW4];
        v.x *= sv; v.y *= sv; v.z *= sv; v.w *= sv;
        ((float4*)out)[i] = v;
    }
}

// ---------------------------------------------------------------- launcher
extern "C" void kernel_launch(void* const* d_in, const int* in_sizes, int n_in,
                              void* d_out, int out_size, void* d_ws, size_t ws_size,
                              hipStream_t stream) {
    const float* x     = (const float*)d_in[0];
    const float* w_sq  = (const float*)d_in[1];
    const float* w_ac1 = (const float*)d_in[2];
    const float* w_ex  = (const float*)d_in[3];
    const float* abn_g = (const float*)d_in[4];
    const float* abn_b = (const float*)d_in[5];
    const float* abn_m = (const float*)d_in[6];
    const float* abn_v = (const float*)d_in[7];
    const float* w_c1  = (const float*)d_in[8];
    const float* bn1_g = (const float*)d_in[9];
    const float* bn1_b = (const float*)d_in[10];
    const float* bn1_m = (const float*)d_in[11];
    const float* bn1_v = (const float*)d_in[12];
    const float* w_c2  = (const float*)d_in[13];
    const float* w_c8s = (const float*)d_in[14];
    const float* b_c8s = (const float*)d_in[15];
    const float* w_c8t = (const float*)d_in[16];
    const float* b_c8t = (const float*)d_in[17];
    const float* w_cs  = (const float*)d_in[18];
    const float* b_cs  = (const float*)d_in[19];
    const float* w_cst = (const float*)d_in[20];
    const float* b_cst = (const float*)d_in[21];
    const float* w_up  = (const float*)d_in[22];
    const float* b_up  = (const float*)d_in[23];
    const float* w_c3  = (const float*)d_in[24];
    const float* bn3_g = (const float*)d_in[25];
    const float* bn3_b = (const float*)d_in[26];
    const float* bn3_m = (const float*)d_in[27];
    const float* bn3_v = (const float*)d_in[28];

    float* ws      = (float*)d_ws;
    float* bot     = ws;                          // 64*16*3136 = 3,211,264
    float* xmean   = bot + 64 * 16 * HW;          // 16384
    float* geff    = xmean + 64 * 256;            // 16384
    float* statsB  = geff + 64 * 256;             // 9216
    float* statsCB = statsB + 64 * 16 * 9;        // 9216
    float* st      = statsCB + 64 * 16 * 9;       // 16384   (~12.5 MB total)

    k_mean<<<NTF * CCH, 256, 0, stream>>>(x, xmean);
    k_excite<<<1, 256, 0, stream>>>(xmean, w_sq, w_ac1, w_ex,
                                    abn_g, abn_b, abn_m, abn_v, geff);
    k_bottleneck<<<dim3(7, 64), 256, 0, stream>>>(x, geff, w_c1, bn1_g, bn1_b,
                                                  bn1_m, bn1_v, bot);
    k_dwstats<<<NTF * RCH, 256, 0, stream>>>(bot, w_c2, statsB, statsCB);
    k_finish<<<1, 256, 0, stream>>>(statsB, statsCB, w_c8s, b_c8s, w_c8t, b_c8t,
                                    w_cs, b_cs, w_cst, b_cst, w_up, b_up, w_c3,
                                    bn3_g, bn3_b, bn3_m, bn3_v, geff, st);
    k_scale_out<<<2048, 256, 0, stream>>>(x, st, (float*)d_out);
}